// Round 1
// baseline (13219.394 us; speedup 1.0000x reference)
//
#include <hip/hip_runtime.h>
#include <math.h>

#define VSZ 32000
#define EDIM 128
#define HDIM 256
#define BSZ 256
#define SLEN 256
#define ANUM 8
#define SALEN 32
#define G3 768          // 3*H
#define KD 384          // E + H
#define KB4 96          // KD/4
#define TB 8            // sequences per block

// workspace float offsets
#define WT_STRIDE (KB4 * G3 * 4)            // 294912 floats per encoder
#define OFF_WT 0
#define OFF_HWT (4 * WT_STRIDE)             // 1179648
#define HWT_SIZE (1024 * HDIM)              // 262144
#define OFF_STATE (OFF_HWT + HWT_SIZE)      // [256][768]
#define OFF_ACT (OFF_STATE + BSZ * G3)      // [2048][256]

__global__ void prep_wt(const float* __restrict__ Wih, const float* __restrict__ Whh,
                        float* __restrict__ WT) {
    int idx = blockIdx.x * 256 + threadIdx.x;
    const int total = 4 * WT_STRIDE;
    if (idx >= total) return;
    int enc = idx / WT_STRIDE;
    int rem = idx % WT_STRIDE;
    int kb  = rem / (G3 * 4);
    int r   = (rem >> 2) % G3;
    int kk  = rem & 3;
    int k   = kb * 4 + kk;
    float v;
    if (k < EDIM) v = Wih[enc * G3 * EDIM + r * EDIM + k];
    else          v = Whh[enc * G3 * HDIM + r * HDIM + (k - EDIM)];
    WT[idx] = v;
}

__global__ void prep_hwt(const float* __restrict__ hW, float* __restrict__ hWT) {
    int idx = blockIdx.x * 256 + threadIdx.x;
    if (idx >= HWT_SIZE) return;
    int k = idx >> 8;       // 0..1023
    int j = idx & 255;      // 0..255
    hWT[idx] = hW[j * 1024 + k];
}

__global__ void __launch_bounds__(256)
gru_kernel(const int* __restrict__ obs_t, const int* __restrict__ obs_l,
           const int* __restrict__ look_t, const int* __restrict__ look_l,
           const int* __restrict__ inv_t, const int* __restrict__ inv_l,
           const int* __restrict__ act_t, const int* __restrict__ act_l,
           const float* __restrict__ emb, const float* __restrict__ bih,
           const float* __restrict__ bhh, const float* __restrict__ WT,
           float* __restrict__ state, float* __restrict__ act_out) {
    int bid = blockIdx.x;
    int enc, tile, S;
    const int* toks;
    const int* lens;
    if (bid < 96) {
        enc = bid / 32; tile = bid % 32; S = SLEN;
        toks = (enc == 0) ? obs_t : (enc == 1) ? look_t : inv_t;
        lens = (enc == 0) ? obs_l : (enc == 1) ? look_l : inv_l;
    } else {
        enc = 3; tile = bid - 96; S = SALEN;
        toks = act_t; lens = act_l;
    }
    const int j = threadIdx.x;   // hidden channel owned by this thread

    __shared__ __align__(16) float xh[TB][KD];   // [seq][ x(128) | h(256) ]

    // init h = 0 (both LDS copy and register copy)
    float hreg[TB];
#pragma unroll
    for (int s = 0; s < TB; ++s) { xh[s][EDIM + j] = 0.f; hreg[s] = 0.f; }

    // lengths (uniform across threads)
    int len_r[TB];
    int maxlen = 1;
#pragma unroll
    for (int s = 0; s < TB; ++s) {
        int l = lens[tile * TB + s];
        if (l < 1) l = 1;
        len_r[s] = l;
        if (l > maxlen) maxlen = l;
    }

    // biases for this channel
    const float* bihe = bih + enc * G3;
    const float* bhhe = bhh + enc * G3;
    const float br  = bihe[j] + bhhe[j];
    const float bz  = bihe[j + HDIM] + bhhe[j + HDIM];
    const float bin = bihe[j + 2 * HDIM];
    const float bhn = bhhe[j + 2 * HDIM];
    const float* WTe = WT + enc * WT_STRIDE;

    __syncthreads();

    for (int t = 0; t < maxlen; ++t) {
        // load x_t = emb[token] into LDS (x part only)
#pragma unroll
        for (int i = 0; i < 4; ++i) {
            int idx = i * 256 + j;
            int s = idx >> 7;        // /128
            int e = idx & 127;
            int tk = toks[(tile * TB + s) * S + t];
            xh[s][e] = emb[tk * EDIM + e];
        }
        __syncthreads();

        float ar[TB], az[TB], ain[TB], ahn[TB];
#pragma unroll
        for (int s = 0; s < TB; ++s) { ar[s] = br; az[s] = bz; ain[s] = bin; ahn[s] = bhn; }

        // x contribution: kb 0..31
        for (int kb = 0; kb < EDIM / 4; ++kb) {
            const float* rowb = WTe + kb * (G3 * 4);
            const float4 wr = *(const float4*)(rowb + 4 * j);
            const float4 wz = *(const float4*)(rowb + 4 * (j + HDIM));
            const float4 wn = *(const float4*)(rowb + 4 * (j + 2 * HDIM));
#pragma unroll
            for (int s = 0; s < TB; ++s) {
                const float4 v = *(const float4*)(&xh[s][4 * kb]);
                ar[s]  += wr.x * v.x + wr.y * v.y + wr.z * v.z + wr.w * v.w;
                az[s]  += wz.x * v.x + wz.y * v.y + wz.z * v.z + wz.w * v.w;
                ain[s] += wn.x * v.x + wn.y * v.y + wn.z * v.z + wn.w * v.w;
            }
        }
        // h contribution: kb 32..95
        for (int kb = EDIM / 4; kb < KB4; ++kb) {
            const float* rowb = WTe + kb * (G3 * 4);
            const float4 wr = *(const float4*)(rowb + 4 * j);
            const float4 wz = *(const float4*)(rowb + 4 * (j + HDIM));
            const float4 wn = *(const float4*)(rowb + 4 * (j + 2 * HDIM));
#pragma unroll
            for (int s = 0; s < TB; ++s) {
                const float4 v = *(const float4*)(&xh[s][4 * kb]);
                ar[s]  += wr.x * v.x + wr.y * v.y + wr.z * v.z + wr.w * v.w;
                az[s]  += wz.x * v.x + wz.y * v.y + wz.z * v.z + wz.w * v.w;
                ahn[s] += wn.x * v.x + wn.y * v.y + wn.z * v.z + wn.w * v.w;
            }
        }

        // gates + state update (registers)
        float hnew[TB];
#pragma unroll
        for (int s = 0; s < TB; ++s) {
            float r = 1.f / (1.f + expf(-ar[s]));
            float z = 1.f / (1.f + expf(-az[s]));
            float n = tanhf(ain[s] + r * ahn[s]);
            float hv = (1.f - z) * n + z * hreg[s];
            hnew[s] = (t < len_r[s]) ? hv : hreg[s];
        }
        __syncthreads();   // all reads of h done before overwrite
#pragma unroll
        for (int s = 0; s < TB; ++s) { hreg[s] = hnew[s]; xh[s][EDIM + j] = hnew[s]; }
        // next iteration's first __syncthreads orders these writes before reads
    }

    // write outputs
#pragma unroll
    for (int s = 0; s < TB; ++s) {
        int sg = tile * TB + s;
        if (enc < 3) state[sg * G3 + enc * HDIM + j] = hreg[s];
        else         act_out[sg * HDIM + j] = hreg[s];
    }
}

__global__ void __launch_bounds__(256)
mlp_kernel(const float* __restrict__ state, const float* __restrict__ act_out,
           const float* __restrict__ hWT, const float* __restrict__ hb,
           const float* __restrict__ sW, const float* __restrict__ sb,
           float* __restrict__ q) {
    int b = blockIdx.x;          // 0..255
    int j = threadIdx.x;         // 0..255
    __shared__ float st[G3];
    __shared__ float ab[ANUM][HDIM];
#pragma unroll
    for (int i = 0; i < 3; ++i) st[i * 256 + j] = state[b * G3 + i * 256 + j];
#pragma unroll
    for (int i = 0; i < ANUM; ++i) ab[i][j] = act_out[(b * ANUM + i) * HDIM + j];
    __syncthreads();

    float accS = 0.f;
#pragma unroll 4
    for (int k = 0; k < G3; ++k) accS += st[k] * hWT[k * HDIM + j];

    float accA[ANUM];
#pragma unroll
    for (int i = 0; i < ANUM; ++i) accA[i] = 0.f;
    for (int k = 0; k < HDIM; ++k) {
        float w = hWT[(G3 + k) * HDIM + j];
#pragma unroll
        for (int i = 0; i < ANUM; ++i) accA[i] += ab[i][k] * w;
    }

    float base = hb[j] + accS;
    float p[ANUM];
#pragma unroll
    for (int i = 0; i < ANUM; ++i) {
        float zz = base + accA[i];
        zz = zz > 0.f ? zz : 0.f;
        p[i] = zz * sW[j];
    }

    __shared__ float wsum[ANUM][4];
#pragma unroll
    for (int i = 0; i < ANUM; ++i) {
        float v = p[i];
        for (int off = 32; off >= 1; off >>= 1) v += __shfl_down(v, off, 64);
        if ((j & 63) == 0) wsum[i][j >> 6] = v;
    }
    __syncthreads();
    if (j < ANUM) q[b * ANUM + j] = wsum[j][0] + wsum[j][1] + wsum[j][2] + wsum[j][3] + sb[0];
}

extern "C" void kernel_launch(void* const* d_in, const int* in_sizes, int n_in,
                              void* d_out, int out_size, void* d_ws, size_t ws_size,
                              hipStream_t stream) {
    const int* obs_t  = (const int*)d_in[0];
    const int* obs_l  = (const int*)d_in[1];
    const int* look_t = (const int*)d_in[2];
    const int* look_l = (const int*)d_in[3];
    const int* inv_t  = (const int*)d_in[4];
    const int* inv_l  = (const int*)d_in[5];
    const int* act_t  = (const int*)d_in[6];
    const int* act_l  = (const int*)d_in[7];
    const float* emb  = (const float*)d_in[8];
    const float* Wih  = (const float*)d_in[9];
    const float* Whh  = (const float*)d_in[10];
    const float* bih  = (const float*)d_in[11];
    const float* bhh  = (const float*)d_in[12];
    const float* hW   = (const float*)d_in[13];
    const float* hb   = (const float*)d_in[14];
    const float* sW   = (const float*)d_in[15];
    const float* sb   = (const float*)d_in[16];

    float* ws    = (float*)d_ws;
    float* WT    = ws + OFF_WT;
    float* hWT   = ws + OFF_HWT;
    float* state = ws + OFF_STATE;
    float* act_o = ws + OFF_ACT;

    prep_wt<<<(4 * WT_STRIDE + 255) / 256, 256, 0, stream>>>(Wih, Whh, WT);
    prep_hwt<<<(HWT_SIZE + 255) / 256, 256, 0, stream>>>(hW, hWT);
    gru_kernel<<<352, 256, 0, stream>>>(obs_t, obs_l, look_t, look_l, inv_t, inv_l,
                                        act_t, act_l, emb, bih, bhh, WT, state, act_o);
    mlp_kernel<<<256, 256, 0, stream>>>(state, act_o, hWT, hb, sW, sb, (float*)d_out);
}

// Round 2
// 5784.116 us; speedup vs baseline: 2.2855x; 2.2855x over previous
//
#include <hip/hip_runtime.h>
#include <math.h>

#define VSZ 32000
#define EDIM 128
#define HDIM 256
#define BSZ 256
#define SLEN 256
#define ANUM 8
#define SALEN 32
#define G3 768          // 3*H
#define KD 384          // E + H
#define KB4 96          // KD/4 (number of float4 blocks along K)
#define TB 8            // sequences per block

// workspace float offsets
#define WT_STRIDE (KB4 * G3 * 4)            // 294912 floats per encoder
#define OFF_WT 0
#define OFF_HWT (4 * WT_STRIDE)             // 1179648
#define HWT_SIZE (1024 * HDIM)              // 262144
#define OFF_STATE (OFF_HWT + HWT_SIZE)      // [256][768]
#define OFF_ACT (OFF_STATE + BSZ * G3)      // [2048][256]

__global__ void prep_wt(const float* __restrict__ Wih, const float* __restrict__ Whh,
                        float* __restrict__ WT) {
    int idx = blockIdx.x * 256 + threadIdx.x;
    const int total = 4 * WT_STRIDE;
    if (idx >= total) return;
    int enc = idx / WT_STRIDE;
    int rem = idx % WT_STRIDE;
    int kb  = rem / (G3 * 4);
    int r   = (rem >> 2) % G3;
    int kk  = rem & 3;
    int k   = kb * 4 + kk;
    float v;
    if (k < EDIM) v = Wih[enc * G3 * EDIM + r * EDIM + k];
    else          v = Whh[enc * G3 * HDIM + r * HDIM + (k - EDIM)];
    WT[idx] = v;
}

__global__ void prep_hwt(const float* __restrict__ hW, float* __restrict__ hWT) {
    int idx = blockIdx.x * 256 + threadIdx.x;
    if (idx >= HWT_SIZE) return;
    int k = idx >> 8;       // 0..1023
    int j = idx & 255;      // 0..255
    hWT[idx] = hW[j * 1024 + k];
}

// Block: 1024 threads. wave w (0..15), lane l (0..63).
//   j  = w*16 + (l&15)   : hidden channel (0..255)
//   ks = l>>4            : K-slice (0..3); slice handles kb = 4*i + ks, i=0..23
// The 4 K-slices of channel j are lanes {l, l^16, l^32, l^48} of the same wave
// -> reduction = 2x __shfl_xor, no LDS partials.
__global__ void __launch_bounds__(1024)
gru_kernel(const int* __restrict__ obs_t, const int* __restrict__ obs_l,
           const int* __restrict__ look_t, const int* __restrict__ look_l,
           const int* __restrict__ inv_t, const int* __restrict__ inv_l,
           const int* __restrict__ act_t, const int* __restrict__ act_l,
           const float* __restrict__ emb, const float* __restrict__ bih,
           const float* __restrict__ bhh, const float* __restrict__ WT,
           float* __restrict__ state, float* __restrict__ act_out) {
    int bid = blockIdx.x;
    int enc, tile, S;
    const int* toks;
    const int* lens;
    if (bid < 96) {
        enc = bid / 32; tile = bid % 32; S = SLEN;
        toks = (enc == 0) ? obs_t : (enc == 1) ? look_t : inv_t;
        lens = (enc == 0) ? obs_l : (enc == 1) ? look_l : inv_l;
    } else {
        enc = 3; tile = bid - 96; S = SALEN;
        toks = act_t; lens = act_l;
    }
    const int tid = threadIdx.x;
    const int ln  = tid & 63;
    const int wv  = tid >> 6;
    const int j   = (wv << 4) | (ln & 15);   // channel
    const int ks  = ln >> 4;                 // K-slice

    __shared__ __align__(16) float xh[TB][KD];   // [seq][ x(128) | h(256) ]  12.3KB

    // init h = 0 in LDS
    {
        int s = tid >> 7, c = tid & 127;
        xh[s][EDIM + c] = 0.f;
        xh[s][EDIM + 128 + c] = 0.f;
    }

    // lengths (uniform across threads)
    int len_r[TB];
    int maxlen = 1;
#pragma unroll
    for (int s = 0; s < TB; ++s) {
        int l = lens[tile * TB + s];
        if (l < 1) l = 1;
        len_r[s] = l;
        if (l > maxlen) maxlen = l;
    }

    // biases for this channel (every thread: gates computed redundantly x4)
    const float* bihe = bih + enc * G3;
    const float* bhhe = bhh + enc * G3;
    const float br  = bihe[j] + bhhe[j];
    const float bz  = bihe[j + HDIM] + bhhe[j + HDIM];
    const float bin = bihe[j + 2 * HDIM];
    const float bhn = bhhe[j + 2 * HDIM];
    const float* WTe = WT + enc * WT_STRIDE;

    float hreg[TB];
#pragma unroll
    for (int s = 0; s < TB; ++s) hreg[s] = 0.f;

    __syncthreads();

    for (int t = 0; t < maxlen; ++t) {
        // load x_t = emb[token] into LDS (x part), 1 float per thread
        {
            int s = tid >> 7, e = tid & 127;
            int tk = toks[(tile * TB + s) * S + t];
            xh[s][e] = emb[tk * EDIM + e];
        }
        __syncthreads();   // x_t ready; h_{t-1} ready

        float a_r[TB], a_z[TB], a_nx[TB], a_nh[TB];
#pragma unroll
        for (int s = 0; s < TB; ++s) { a_r[s] = 0.f; a_z[s] = 0.f; a_nx[s] = 0.f; a_nh[s] = 0.f; }

        // x contribution: i=0..7  -> kb = 4i+ks in [0,32)  (k < 128)
#pragma unroll 2
        for (int i = 0; i < 8; ++i) {
            const int kb = 4 * i + ks;
            const float* rowb = WTe + kb * (G3 * 4);
            const float4 wr = *(const float4*)(rowb + 4 * j);
            const float4 wz = *(const float4*)(rowb + 4 * j + 1024);
            const float4 wn = *(const float4*)(rowb + 4 * j + 2048);
#pragma unroll
            for (int s = 0; s < TB; ++s) {
                const float4 v = *(const float4*)(&xh[s][4 * kb]);
                a_r[s]  = fmaf(wr.x, v.x, fmaf(wr.y, v.y, fmaf(wr.z, v.z, fmaf(wr.w, v.w, a_r[s]))));
                a_z[s]  = fmaf(wz.x, v.x, fmaf(wz.y, v.y, fmaf(wz.z, v.z, fmaf(wz.w, v.w, a_z[s]))));
                a_nx[s] = fmaf(wn.x, v.x, fmaf(wn.y, v.y, fmaf(wn.z, v.z, fmaf(wn.w, v.w, a_nx[s]))));
            }
        }
        // h contribution: i=8..23 -> kb in [32,96)  (k >= 128)
#pragma unroll 2
        for (int i = 8; i < 24; ++i) {
            const int kb = 4 * i + ks;
            const float* rowb = WTe + kb * (G3 * 4);
            const float4 wr = *(const float4*)(rowb + 4 * j);
            const float4 wz = *(const float4*)(rowb + 4 * j + 1024);
            const float4 wn = *(const float4*)(rowb + 4 * j + 2048);
#pragma unroll
            for (int s = 0; s < TB; ++s) {
                const float4 v = *(const float4*)(&xh[s][4 * kb]);
                a_r[s]  = fmaf(wr.x, v.x, fmaf(wr.y, v.y, fmaf(wr.z, v.z, fmaf(wr.w, v.w, a_r[s]))));
                a_z[s]  = fmaf(wz.x, v.x, fmaf(wz.y, v.y, fmaf(wz.z, v.z, fmaf(wz.w, v.w, a_z[s]))));
                a_nh[s] = fmaf(wn.x, v.x, fmaf(wn.y, v.y, fmaf(wn.z, v.z, fmaf(wn.w, v.w, a_nh[s]))));
            }
        }

        // butterfly reduce across the 4 K-slices (lanes l^16, l^32)
#pragma unroll
        for (int s = 0; s < TB; ++s) {
            a_r[s]  += __shfl_xor(a_r[s], 16);  a_r[s]  += __shfl_xor(a_r[s], 32);
            a_z[s]  += __shfl_xor(a_z[s], 16);  a_z[s]  += __shfl_xor(a_z[s], 32);
            a_nx[s] += __shfl_xor(a_nx[s], 16); a_nx[s] += __shfl_xor(a_nx[s], 32);
            a_nh[s] += __shfl_xor(a_nh[s], 16); a_nh[s] += __shfl_xor(a_nh[s], 32);
        }

        // gates (every lane has full sums for its j; 4x redundant but barrier-free)
        float hnew[TB];
#pragma unroll
        for (int s = 0; s < TB; ++s) {
            float r = 1.f / (1.f + expf(-(a_r[s] + br)));
            float z = 1.f / (1.f + expf(-(a_z[s] + bz)));
            float n = tanhf(a_nx[s] + bin + r * (a_nh[s] + bhn));
            float hv = (1.f - z) * n + z * hreg[s];
            hnew[s] = (t < len_r[s]) ? hv : hreg[s];
        }
        __syncthreads();   // all xh reads of this step done before h overwrite

        // each K-slice group writes 2 of the 8 sequences' h
        {
            int s0 = 2 * ks;
            xh[s0][EDIM + j]     = hnew[s0];
            xh[s0 + 1][EDIM + j] = hnew[s0 + 1];
        }
#pragma unroll
        for (int s = 0; s < TB; ++s) hreg[s] = hnew[s];
        // next iteration: x-load writes disjoint region, then barrier -> dots see new h
    }

    // write outputs (one K-slice group only, to avoid redundant stores)
    if (ks == 0) {
#pragma unroll
        for (int s = 0; s < TB; ++s) {
            int sg = tile * TB + s;
            if (enc < 3) state[sg * G3 + enc * HDIM + j] = hreg[s];
            else         act_out[sg * HDIM + j] = hreg[s];
        }
    }
}

__global__ void __launch_bounds__(256)
mlp_kernel(const float* __restrict__ state, const float* __restrict__ act_out,
           const float* __restrict__ hWT, const float* __restrict__ hb,
           const float* __restrict__ sW, const float* __restrict__ sb,
           float* __restrict__ q) {
    int b = blockIdx.x;          // 0..255
    int j = threadIdx.x;         // 0..255
    __shared__ float st[G3];
    __shared__ float ab[ANUM][HDIM];
#pragma unroll
    for (int i = 0; i < 3; ++i) st[i * 256 + j] = state[b * G3 + i * 256 + j];
#pragma unroll
    for (int i = 0; i < ANUM; ++i) ab[i][j] = act_out[(b * ANUM + i) * HDIM + j];
    __syncthreads();

    float accS = 0.f;
#pragma unroll 4
    for (int k = 0; k < G3; ++k) accS += st[k] * hWT[k * HDIM + j];

    float accA[ANUM];
#pragma unroll
    for (int i = 0; i < ANUM; ++i) accA[i] = 0.f;
    for (int k = 0; k < HDIM; ++k) {
        float w = hWT[(G3 + k) * HDIM + j];
#pragma unroll
        for (int i = 0; i < ANUM; ++i) accA[i] += ab[i][k] * w;
    }

    float base = hb[j] + accS;
    float p[ANUM];
#pragma unroll
    for (int i = 0; i < ANUM; ++i) {
        float zz = base + accA[i];
        zz = zz > 0.f ? zz : 0.f;
        p[i] = zz * sW[j];
    }

    __shared__ float wsum[ANUM][4];
#pragma unroll
    for (int i = 0; i < ANUM; ++i) {
        float v = p[i];
        for (int off = 32; off >= 1; off >>= 1) v += __shfl_down(v, off, 64);
        if ((j & 63) == 0) wsum[i][j >> 6] = v;
    }
    __syncthreads();
    if (j < ANUM) q[b * ANUM + j] = wsum[j][0] + wsum[j][1] + wsum[j][2] + wsum[j][3] + sb[0];
}

extern "C" void kernel_launch(void* const* d_in, const int* in_sizes, int n_in,
                              void* d_out, int out_size, void* d_ws, size_t ws_size,
                              hipStream_t stream) {
    const int* obs_t  = (const int*)d_in[0];
    const int* obs_l  = (const int*)d_in[1];
    const int* look_t = (const int*)d_in[2];
    const int* look_l = (const int*)d_in[3];
    const int* inv_t  = (const int*)d_in[4];
    const int* inv_l  = (const int*)d_in[5];
    const int* act_t  = (const int*)d_in[6];
    const int* act_l  = (const int*)d_in[7];
    const float* emb  = (const float*)d_in[8];
    const float* Wih  = (const float*)d_in[9];
    const float* Whh  = (const float*)d_in[10];
    const float* bih  = (const float*)d_in[11];
    const float* bhh  = (const float*)d_in[12];
    const float* hW   = (const float*)d_in[13];
    const float* hb   = (const float*)d_in[14];
    const float* sW   = (const float*)d_in[15];
    const float* sb   = (const float*)d_in[16];

    float* ws    = (float*)d_ws;
    float* WT    = ws + OFF_WT;
    float* hWT   = ws + OFF_HWT;
    float* state = ws + OFF_STATE;
    float* act_o = ws + OFF_ACT;

    prep_wt<<<(4 * WT_STRIDE + 255) / 256, 256, 0, stream>>>(Wih, Whh, WT);
    prep_hwt<<<(HWT_SIZE + 255) / 256, 256, 0, stream>>>(hW, hWT);
    gru_kernel<<<352, 1024, 0, stream>>>(obs_t, obs_l, look_t, look_l, inv_t, inv_l,
                                         act_t, act_l, emb, bih, bhh, WT, state, act_o);
    mlp_kernel<<<256, 256, 0, stream>>>(state, act_o, hWT, hb, sW, sb, (float*)d_out);
}